// Round 1
// baseline (182.956 us; speedup 1.0000x reference)
//
#include <hip/hip_runtime.h>
#include <math.h>

// Problem constants (B=16, T=2048, D=1024, K=8)
#define BT   32768   // B*T rows
#define DD   1024    // D
#define DV   256     // float4 per row (D/4)
#define KC   8       // clusters

// ---------------------------------------------------------------------------
// Kernel 1: partial column sums of x (BT x DD), accumulated atomically into
// colsum[0..DD-1]. Thread t owns float4-column t (4 scalar columns), so the
// per-block partial sums need no intra-block reduction.
// ---------------------------------------------------------------------------
__global__ __launch_bounds__(256) void k1_colsum(const float* __restrict__ x,
                                                 float* __restrict__ colsum,
                                                 int rows_per_blk) {
    const int tid = threadIdx.x;
    const float4* xv = (const float4*)x;
    const long row0 = (long)blockIdx.x * rows_per_blk;
    float4 acc = make_float4(0.f, 0.f, 0.f, 0.f);
    for (int r = 0; r < rows_per_blk; ++r) {
        float4 v = xv[(row0 + r) * DV + tid];
        acc.x += v.x; acc.y += v.y; acc.z += v.z; acc.w += v.w;
    }
    const int c = tid * 4;
    atomicAdd(&colsum[c + 0], acc.x);
    atomicAdd(&colsum[c + 1], acc.y);
    atomicAdd(&colsum[c + 2], acc.z);
    atomicAdd(&colsum[c + 3], acc.w);
}

// ---------------------------------------------------------------------------
// Kernel 2: x_mean -> RMS distances to the K cluster means -> softmax
// responsibilities r[0..K-1]. Single block; cost is negligible.
// ---------------------------------------------------------------------------
__global__ __launch_bounds__(256) void k2_resp(const float* __restrict__ colsum,
                                               const float* __restrict__ mus,
                                               const float* __restrict__ ws,
                                               float* __restrict__ r_out) {
    const int tid = threadIdx.x;
    const float inv_bt = 1.0f / (float)BT;
    float4 s = ((const float4*)colsum)[tid];
    float m[4] = { s.x * inv_bt, s.y * inv_bt, s.z * inv_bt, s.w * inv_bt };

    float part[KC];
#pragma unroll
    for (int k = 0; k < KC; ++k) {
        float4 mu = ((const float4*)mus)[k * DV + tid];
        float d0 = m[0] - mu.x, d1 = m[1] - mu.y;
        float d2 = m[2] - mu.z, d3 = m[3] - mu.w;
        part[k] = d0 * d0 + d1 * d1 + d2 * d2 + d3 * d3;
    }

    __shared__ float lds[KC][4];
    const int lane = tid & 63, wv = tid >> 6;
#pragma unroll
    for (int k = 0; k < KC; ++k) {
        float v = part[k];
#pragma unroll
        for (int off = 32; off > 0; off >>= 1) v += __shfl_down(v, off, 64);
        if (lane == 0) lds[k][wv] = v;
    }
    __syncthreads();
    if (tid == 0) {
        float logits[KC], mx = -1e30f;
#pragma unroll
        for (int k = 0; k < KC; ++k) {
            float tot = lds[k][0] + lds[k][1] + lds[k][2] + lds[k][3];
            float dist = sqrtf(tot * (1.0f / (float)DD));
            logits[k] = logf(ws[k]) - dist;
            mx = fmaxf(mx, logits[k]);
        }
        float se = 0.f, e[KC];
#pragma unroll
        for (int k = 0; k < KC; ++k) { e[k] = expf(logits[k] - mx); se += e[k]; }
        float is = 1.f / se;
#pragma unroll
        for (int k = 0; k < KC; ++k) r_out[k] = e[k] * is;
    }
}

// ---------------------------------------------------------------------------
// Kernel 3: main elementwise pass. Thread's scalar columns are fixed
// (tid*4 .. tid*4+3), so tau*log2(e), alpha, mu[k][e], r[k] are loaded once
// and live in registers across all row iterations. Inner loop is:
//   float4 load -> 8x (sub/abs/mul/v_exp_f32/fma) -> gelu-tanh -> float4 store
// ---------------------------------------------------------------------------
__global__ __launch_bounds__(256) void k3_main(const float* __restrict__ x,
                                               const float* __restrict__ mus,
                                               const float* __restrict__ log_tau,
                                               const float* __restrict__ log_blend,
                                               const float* __restrict__ rbuf,
                                               float* __restrict__ out,
                                               int rows_per_blk) {
    const int tid = threadIdx.x;
    const float LOG2E = 1.44269504f;

    // Per-column constants (hoisted out of the row loop).
    float4 lt = ((const float4*)log_tau)[tid];
    float4 lb = ((const float4*)log_blend)[tid];
    float tl[4], al[4];
    // tau = exp(log_tau); tl = tau * log2(e) so famil exp uses native exp2.
    tl[0] = __builtin_amdgcn_exp2f(lt.x * LOG2E) * LOG2E;
    tl[1] = __builtin_amdgcn_exp2f(lt.y * LOG2E) * LOG2E;
    tl[2] = __builtin_amdgcn_exp2f(lt.z * LOG2E) * LOG2E;
    tl[3] = __builtin_amdgcn_exp2f(lt.w * LOG2E) * LOG2E;
    // alpha = sigmoid(log_blend)
    al[0] = 1.f / (1.f + __builtin_amdgcn_exp2f(-lb.x * LOG2E));
    al[1] = 1.f / (1.f + __builtin_amdgcn_exp2f(-lb.y * LOG2E));
    al[2] = 1.f / (1.f + __builtin_amdgcn_exp2f(-lb.z * LOG2E));
    al[3] = 1.f / (1.f + __builtin_amdgcn_exp2f(-lb.w * LOG2E));

    float mu[KC][4];
#pragma unroll
    for (int k = 0; k < KC; ++k) {
        float4 m4 = ((const float4*)mus)[k * DV + tid];
        mu[k][0] = m4.x; mu[k][1] = m4.y; mu[k][2] = m4.z; mu[k][3] = m4.w;
    }
    float rk[KC];
#pragma unroll
    for (int k = 0; k < KC; ++k) rk[k] = rbuf[k];

    const float4* xv = (const float4*)x;
    float4* ov = (float4*)out;
    const long row0 = (long)blockIdx.x * rows_per_blk;

    for (int rr = 0; rr < rows_per_blk; ++rr) {
        const long idx = (row0 + rr) * DV + tid;
        float4 v = xv[idx];
        float xin[4] = { v.x, v.y, v.z, v.w };
        float o[4];
#pragma unroll
        for (int e = 0; e < 4; ++e) {
            float xe = xin[e];
            float fam = 0.f;
#pragma unroll
            for (int k = 0; k < KC; ++k) {
                fam += rk[k] * __builtin_amdgcn_exp2f(-tl[e] * fabsf(xe - mu[k][e]));
            }
            float y = xe * (1.f - al[e] * fam);
            // gelu_tanh(y) = 0.5*y*(1 + tanh(c*(y + 0.044715*y^3)))
            float z = 0.79788456f * (y + 0.044715f * y * y * y);
            // tanh(z) = 1 - 2/(exp(2z)+1); exp via native exp2
            float e2 = __builtin_amdgcn_exp2f(2.88539008f * z);
            float th = 1.f - 2.f * __builtin_amdgcn_rcpf(e2 + 1.f);
            o[e] = 0.5f * y * (1.f + th);
        }
        ov[idx] = make_float4(o[0], o[1], o[2], o[3]);
    }
}

extern "C" void kernel_launch(void* const* d_in, const int* in_sizes, int n_in,
                              void* d_out, int out_size, void* d_ws, size_t ws_size,
                              hipStream_t stream) {
    const float* x         = (const float*)d_in[0];
    const float* mus       = (const float*)d_in[1];
    const float* ws        = (const float*)d_in[2];
    const float* log_tau   = (const float*)d_in[3];
    const float* log_blend = (const float*)d_in[4];
    float* out = (float*)d_out;

    float* colsum = (float*)d_ws;        // DD floats (4 KB)
    float* rbuf   = colsum + DD;         // KC floats

    // Zero the atomic accumulator every call (deterministic, capture-safe).
    hipMemsetAsync(colsum, 0, DD * sizeof(float), stream);

    const int g1 = 1024;                 // 32 rows per block
    k1_colsum<<<g1, 256, 0, stream>>>(x, colsum, BT / g1);

    k2_resp<<<1, 256, 0, stream>>>(colsum, mus, ws, rbuf);

    const int g3 = 2048;                 // 16 rows per block
    k3_main<<<g3, 256, 0, stream>>>(x, mus, log_tau, log_blend, rbuf, out, BT / g3);
}

// Round 3
// 96.911 us; speedup vs baseline: 1.8879x; 1.8879x over previous
//
#include <hip/hip_runtime.h>
#include <math.h>

// Problem constants (B=16, T=2048, D=1024, K=8)
#define BT   32768   // B*T rows
#define DD   1024    // D
#define DV   256     // float4 per row (D/4)
#define KC   8       // clusters
#define NREP 8       // colsum replicas (atomic contention spreader)

// clang native vector type — required by __builtin_nontemporal_store
// (HIP's float4 is a class and is rejected by the builtin).
typedef float fv4 __attribute__((ext_vector_type(4)));

// ---------------------------------------------------------------------------
// Kernel 1: partial column sums of x (BT x DD). Thread t owns float4-column t.
// 8-deep explicit load batching keeps 8 float4 loads in flight per thread
// (the round-1 version had VGPR=8 -> ONE outstanding load -> latency-bound,
// 594 GB/s). Epilogue atomicAdds into one of NREP replicas so per-address
// contention is 512/NREP = 64 instead of 1024.
// ---------------------------------------------------------------------------
__global__ __launch_bounds__(256) void k1_colsum(const float* __restrict__ x,
                                                 float* __restrict__ colsum_rep,
                                                 int rows_per_blk) {
    const int tid = threadIdx.x;
    const fv4* xv = (const fv4*)x;
    const long row0 = (long)blockIdx.x * rows_per_blk;
    fv4 acc = (fv4)(0.f);

    for (int r = 0; r < rows_per_blk; r += 8) {
        fv4 v[8];
#pragma unroll
        for (int i = 0; i < 8; ++i)
            v[i] = xv[(row0 + r + i) * DV + tid];
#pragma unroll
        for (int i = 0; i < 8; ++i) acc += v[i];
    }

    float* dst = colsum_rep + (long)(blockIdx.x & (NREP - 1)) * DD;
    const int c = tid * 4;
    atomicAdd(&dst[c + 0], acc.x);
    atomicAdd(&dst[c + 1], acc.y);
    atomicAdd(&dst[c + 2], acc.z);
    atomicAdd(&dst[c + 3], acc.w);
}

// ---------------------------------------------------------------------------
// Kernel 2: fold the NREP colsum replicas -> x_mean -> RMS distances to the K
// cluster means -> softmax responsibilities r[0..K-1]. Single block, trivial.
// ---------------------------------------------------------------------------
__global__ __launch_bounds__(256) void k2_resp(const float* __restrict__ colsum_rep,
                                               const float* __restrict__ mus,
                                               const float* __restrict__ ws,
                                               float* __restrict__ r_out) {
    const int tid = threadIdx.x;
    const float inv_bt = 1.0f / (float)BT;

    fv4 s = (fv4)(0.f);
#pragma unroll
    for (int rep = 0; rep < NREP; ++rep)
        s += ((const fv4*)colsum_rep)[rep * DV + tid];
    float m[4] = { s.x * inv_bt, s.y * inv_bt, s.z * inv_bt, s.w * inv_bt };

    float part[KC];
#pragma unroll
    for (int k = 0; k < KC; ++k) {
        fv4 mu = ((const fv4*)mus)[k * DV + tid];
        float d0 = m[0] - mu.x, d1 = m[1] - mu.y;
        float d2 = m[2] - mu.z, d3 = m[3] - mu.w;
        part[k] = d0 * d0 + d1 * d1 + d2 * d2 + d3 * d3;
    }

    __shared__ float lds[KC][4];
    const int lane = tid & 63, wv = tid >> 6;
#pragma unroll
    for (int k = 0; k < KC; ++k) {
        float v = part[k];
#pragma unroll
        for (int off = 32; off > 0; off >>= 1) v += __shfl_down(v, off, 64);
        if (lane == 0) lds[k][wv] = v;
    }
    __syncthreads();
    if (tid == 0) {
        float logits[KC], mx = -1e30f;
#pragma unroll
        for (int k = 0; k < KC; ++k) {
            float tot = lds[k][0] + lds[k][1] + lds[k][2] + lds[k][3];
            float dist = sqrtf(tot * (1.0f / (float)DD));
            logits[k] = logf(ws[k]) - dist;
            mx = fmaxf(mx, logits[k]);
        }
        float se = 0.f, e[KC];
#pragma unroll
        for (int k = 0; k < KC; ++k) { e[k] = expf(logits[k] - mx); se += e[k]; }
        float is = 1.f / se;
#pragma unroll
        for (int k = 0; k < KC; ++k) r_out[k] = e[k] * is;
    }
}

// ---------------------------------------------------------------------------
// Kernel 3: main elementwise pass. Thread's scalar columns are fixed
// (tid*4 .. tid*4+3), so tau*log2(e), alpha, mu[k][e], r[k] live in registers
// across all row iterations. Non-temporal store keeps x resident in the
// Infinity Cache (x + out = 268 MB > 256 MB L3 otherwise thrashes).
// ---------------------------------------------------------------------------
__global__ __launch_bounds__(256) void k3_main(const float* __restrict__ x,
                                               const float* __restrict__ mus,
                                               const float* __restrict__ log_tau,
                                               const float* __restrict__ log_blend,
                                               const float* __restrict__ rbuf,
                                               float* __restrict__ out,
                                               int rows_per_blk) {
    const int tid = threadIdx.x;
    const float LOG2E = 1.44269504f;

    fv4 lt = ((const fv4*)log_tau)[tid];
    fv4 lb = ((const fv4*)log_blend)[tid];
    float tl[4], al[4];
    tl[0] = __builtin_amdgcn_exp2f(lt.x * LOG2E) * LOG2E;
    tl[1] = __builtin_amdgcn_exp2f(lt.y * LOG2E) * LOG2E;
    tl[2] = __builtin_amdgcn_exp2f(lt.z * LOG2E) * LOG2E;
    tl[3] = __builtin_amdgcn_exp2f(lt.w * LOG2E) * LOG2E;
    al[0] = 1.f / (1.f + __builtin_amdgcn_exp2f(-lb.x * LOG2E));
    al[1] = 1.f / (1.f + __builtin_amdgcn_exp2f(-lb.y * LOG2E));
    al[2] = 1.f / (1.f + __builtin_amdgcn_exp2f(-lb.z * LOG2E));
    al[3] = 1.f / (1.f + __builtin_amdgcn_exp2f(-lb.w * LOG2E));

    float mu[KC][4];
#pragma unroll
    for (int k = 0; k < KC; ++k) {
        fv4 m4 = ((const fv4*)mus)[k * DV + tid];
        mu[k][0] = m4.x; mu[k][1] = m4.y; mu[k][2] = m4.z; mu[k][3] = m4.w;
    }
    float rk[KC];
#pragma unroll
    for (int k = 0; k < KC; ++k) rk[k] = rbuf[k];

    const fv4* xv = (const fv4*)x;
    fv4* ov = (fv4*)out;
    const long row0 = (long)blockIdx.x * rows_per_blk;

    for (int rr = 0; rr < rows_per_blk; ++rr) {
        const long idx = (row0 + rr) * DV + tid;
        fv4 v = xv[idx];
        float xin[4] = { v.x, v.y, v.z, v.w };
        float o[4];
#pragma unroll
        for (int e = 0; e < 4; ++e) {
            float xe = xin[e];
            float fam = 0.f;
#pragma unroll
            for (int k = 0; k < KC; ++k) {
                fam += rk[k] * __builtin_amdgcn_exp2f(-tl[e] * fabsf(xe - mu[k][e]));
            }
            float y = xe * (1.f - al[e] * fam);
            float z = 0.79788456f * (y + 0.044715f * y * y * y);
            float e2 = __builtin_amdgcn_exp2f(2.88539008f * z);
            float th = 1.f - 2.f * __builtin_amdgcn_rcpf(e2 + 1.f);
            o[e] = 0.5f * y * (1.f + th);
        }
        fv4 res; res.x = o[0]; res.y = o[1]; res.z = o[2]; res.w = o[3];
        __builtin_nontemporal_store(res, &ov[idx]);
    }
}

extern "C" void kernel_launch(void* const* d_in, const int* in_sizes, int n_in,
                              void* d_out, int out_size, void* d_ws, size_t ws_size,
                              hipStream_t stream) {
    const float* x         = (const float*)d_in[0];
    const float* mus       = (const float*)d_in[1];
    const float* ws        = (const float*)d_in[2];
    const float* log_tau   = (const float*)d_in[3];
    const float* log_blend = (const float*)d_in[4];
    float* out = (float*)d_out;

    float* colsum_rep = (float*)d_ws;           // NREP * DD floats (32 KB)
    float* rbuf       = colsum_rep + NREP * DD; // KC floats

    // Zero the atomic accumulators every call (deterministic, capture-safe).
    (void)hipMemsetAsync(colsum_rep, 0, NREP * DD * sizeof(float), stream);

    const int g1 = 512;                  // 64 rows per block
    k1_colsum<<<g1, 256, 0, stream>>>(x, colsum_rep, BT / g1);

    k2_resp<<<1, 256, 0, stream>>>(colsum_rep, mus, ws, rbuf);

    const int g3 = 2048;                 // 16 rows per block
    k3_main<<<g3, 256, 0, stream>>>(x, mus, log_tau, log_blend, rbuf, out, BT / g3);
}